// Round 1
// baseline (363.661 us; speedup 1.0000x reference)
//
#include <hip/hip_runtime.h>
#include <math.h>

#define MM 512
#define KK 100000
#define NB1 1024   // pass1/pass2 grid

// ws float layout:
// [0..512)    v = W^T a1
// [512..1024) u = W^T a2
// [1024..1536) colsum
// [1536] c   [1537] m   [1538] Z
// [2048..2048+NB1) pmax (per-block partial max of s)
// [4096..4096+KK)  s    (s_i = x_i . v)

__device__ inline float waveSum(float v){
  #pragma unroll
  for(int off = 32; off > 0; off >>= 1) v += __shfl_down(v, off, 64);
  return v;   // total in lane 0
}
__device__ inline float waveMax(float v){
  #pragma unroll
  for(int off = 32; off > 0; off >>= 1) v = fmaxf(v, __shfl_down(v, off, 64));
  return v;
}

// v_j = sum_k W[k,j] a1[k] ; u_j = sum_k W[k,j] a2[k]
// grid: 128 blocks x 512 threads; block handles 4 k-rows of W, coalesced in j.
__global__ __launch_bounds__(512) void k_vu(const float* __restrict__ W,
                                            const float* __restrict__ a,
                                            float* __restrict__ v,
                                            float* __restrict__ u){
  int j  = threadIdx.x;
  int k0 = blockIdx.x * 4;
  float pv = 0.f, pu = 0.f;
  #pragma unroll
  for(int kk = 0; kk < 4; kk++){
    float w = W[(size_t)(k0 + kk) * MM + j];
    pv += w * a[k0 + kk];
    pu += w * a[MM + k0 + kk];
  }
  atomicAdd(&v[j], pv);
  atomicAdd(&u[j], pu);
}

// Pass 1 over x: s_i = x_i . v, column sums, per-block max of s.
__global__ __launch_bounds__(256) void k_pass1(const float* __restrict__ x,
                                               const float* __restrict__ v,
                                               float* __restrict__ s,
                                               float* __restrict__ colsum,
                                               float* __restrict__ pmax){
  __shared__ float lcol[512];
  __shared__ float lmax[4];
  int tid  = threadIdx.x;
  int lane = tid & 63;
  int wid  = tid >> 6;
  int gw   = blockIdx.x * 4 + wid;
  int nw   = gridDim.x * 4;

  const float4* v4 = (const float4*)v;
  float4 v0 = v4[lane];       // cols 4l..4l+3
  float4 v1 = v4[64 + lane];  // cols 256+4l..
  float4 c0 = make_float4(0,0,0,0), c1 = make_float4(0,0,0,0);
  float wmax = -3.4e38f;

  for(int row = gw; row < KK; row += nw){
    const float4* xr = (const float4*)(x + (size_t)row * MM);
    float4 x0 = xr[lane];
    float4 x1 = xr[64 + lane];
    float d = x0.x*v0.x + x0.y*v0.y + x0.z*v0.z + x0.w*v0.w
            + x1.x*v1.x + x1.y*v1.y + x1.z*v1.z + x1.w*v1.w;
    c0.x += x0.x; c0.y += x0.y; c0.z += x0.z; c0.w += x0.w;
    c1.x += x1.x; c1.y += x1.y; c1.z += x1.z; c1.w += x1.w;
    d = waveSum(d);
    if(lane == 0){ s[row] = d; wmax = fmaxf(wmax, d); }
  }

  lcol[tid] = 0.f; lcol[tid + 256] = 0.f;
  __syncthreads();
  atomicAdd(&lcol[lane*4 + 0], c0.x);
  atomicAdd(&lcol[lane*4 + 1], c0.y);
  atomicAdd(&lcol[lane*4 + 2], c0.z);
  atomicAdd(&lcol[lane*4 + 3], c0.w);
  atomicAdd(&lcol[256 + lane*4 + 0], c1.x);
  atomicAdd(&lcol[256 + lane*4 + 1], c1.y);
  atomicAdd(&lcol[256 + lane*4 + 2], c1.z);
  atomicAdd(&lcol[256 + lane*4 + 3], c1.w);
  if(lane == 0) lmax[wid] = wmax;
  __syncthreads();
  atomicAdd(&colsum[tid],       lcol[tid]);
  atomicAdd(&colsum[tid + 256], lcol[tid + 256]);
  if(tid == 0){
    float pm = fmaxf(fmaxf(lmax[0], lmax[1]), fmaxf(lmax[2], lmax[3]));
    pmax[blockIdx.x] = pm;
  }
}

// Single block: c = b.(a1+a2) + (colsum/K).u ; m = max(0, max_i s_i + c)
__global__ __launch_bounds__(512) void k_mid(const float* __restrict__ b,
                                             const float* __restrict__ a,
                                             const float* __restrict__ u,
                                             const float* __restrict__ colsum,
                                             const float* __restrict__ pmax,
                                             float* __restrict__ cm){
  __shared__ float ls[8];
  __shared__ float lm[8];
  int tid = threadIdx.x;
  float t = b[tid] * (a[tid] + a[MM + tid])
          + colsum[tid] * (1.0f / (float)KK) * u[tid];
  float wsum = waveSum(t);
  float mx = -3.4e38f;
  for(int i = tid; i < NB1; i += 512) mx = fmaxf(mx, pmax[i]);
  mx = waveMax(mx);
  if((tid & 63) == 0){ ls[tid >> 6] = wsum; lm[tid >> 6] = mx; }
  __syncthreads();
  if(tid == 0){
    float c = 0.f, m = -3.4e38f;
    #pragma unroll
    for(int i = 0; i < 8; i++){ c += ls[i]; m = fmaxf(m, lm[i]); }
    cm[0] = c;
    cm[1] = fmaxf(0.f, m + c);   // max of relu(s+c)
  }
}

// Z = sum_i exp(relu(s_i + c) - m)
__global__ __launch_bounds__(256) void k_z(const float* __restrict__ s,
                                           const float* __restrict__ cm,
                                           float* __restrict__ Z){
  __shared__ float ls[4];
  float c = cm[0], m = cm[1];
  int tid = threadIdx.x;
  float acc = 0.f;
  for(int i = blockIdx.x * 256 + tid; i < KK; i += gridDim.x * 256)
    acc += __expf(fmaxf(s[i] + c, 0.f) - m);
  acc = waveSum(acc);
  if((tid & 63) == 0) ls[tid >> 6] = acc;
  __syncthreads();
  if(tid == 0) atomicAdd(Z, ls[0] + ls[1] + ls[2] + ls[3]);
}

// Pass 2 over x: out_j = (1/Z) sum_i exp(relu(s_i+c)-m) * x[i,j]
__global__ __launch_bounds__(256) void k_pass2(const float* __restrict__ x,
                                               const float* __restrict__ s,
                                               const float* __restrict__ cm,
                                               const float* __restrict__ Zp,
                                               float* __restrict__ out){
  __shared__ float lout[512];
  int tid  = threadIdx.x;
  int lane = tid & 63;
  int gw   = blockIdx.x * 4 + (tid >> 6);
  int nw   = gridDim.x * 4;
  float c = cm[0], m = cm[1];
  float invZ = 1.0f / Zp[0];
  float4 a0 = make_float4(0,0,0,0), a1 = make_float4(0,0,0,0);

  for(int row = gw; row < KK; row += nw){
    float w = __expf(fmaxf(s[row] + c, 0.f) - m) * invZ;
    const float4* xr = (const float4*)(x + (size_t)row * MM);
    float4 x0 = xr[lane];
    float4 x1 = xr[64 + lane];
    a0.x += w * x0.x; a0.y += w * x0.y; a0.z += w * x0.z; a0.w += w * x0.w;
    a1.x += w * x1.x; a1.y += w * x1.y; a1.z += w * x1.z; a1.w += w * x1.w;
  }

  lout[tid] = 0.f; lout[tid + 256] = 0.f;
  __syncthreads();
  atomicAdd(&lout[lane*4 + 0], a0.x);
  atomicAdd(&lout[lane*4 + 1], a0.y);
  atomicAdd(&lout[lane*4 + 2], a0.z);
  atomicAdd(&lout[lane*4 + 3], a0.w);
  atomicAdd(&lout[256 + lane*4 + 0], a1.x);
  atomicAdd(&lout[256 + lane*4 + 1], a1.y);
  atomicAdd(&lout[256 + lane*4 + 2], a1.z);
  atomicAdd(&lout[256 + lane*4 + 3], a1.w);
  __syncthreads();
  atomicAdd(&out[tid],       lout[tid]);
  atomicAdd(&out[tid + 256], lout[tid + 256]);
}

extern "C" void kernel_launch(void* const* d_in, const int* in_sizes, int n_in,
                              void* d_out, int out_size, void* d_ws, size_t ws_size,
                              hipStream_t stream) {
  const float* x = (const float*)d_in[0];
  const float* W = (const float*)d_in[1];
  const float* b = (const float*)d_in[2];
  const float* a = (const float*)d_in[3];
  float* ws  = (float*)d_ws;
  float* out = (float*)d_out;

  float* v      = ws;
  float* u      = ws + 512;
  float* colsum = ws + 1024;
  float* cm     = ws + 1536;   // c, m
  float* Z      = ws + 1538;
  float* pmax   = ws + 2048;
  float* s      = ws + 4096;

  // zero v,u,colsum,c,m,Z (first 2048 floats) and out
  hipMemsetAsync(ws, 0, 2048 * sizeof(float), stream);
  hipMemsetAsync(d_out, 0, 512 * sizeof(float), stream);

  k_vu   <<<128,  512, 0, stream>>>(W, a, v, u);
  k_pass1<<<NB1,  256, 0, stream>>>(x, v, s, colsum, pmax);
  k_mid  <<<1,    512, 0, stream>>>(b, a, u, colsum, pmax, cm);
  k_z    <<<256,  256, 0, stream>>>(s, cm, Z);
  k_pass2<<<NB1,  256, 0, stream>>>(x, s, cm, Z, out);
}

// Round 2
// 351.687 us; speedup vs baseline: 1.0340x; 1.0340x over previous
//
#include <hip/hip_runtime.h>
#include <math.h>

#define MM 512
#define KK 100000
#define NB1 1024               // pass1/pass2 blocks (4 waves each -> 4096 waves)
#define NW  (NB1 * 4)          // total waves in pass kernels

// ws float layout:
// [0..512)     v = W^T a1
// [512..1024)  u = W^T a2
// [1024]       sumU = sum_i x_i . u
// [1025]       Z    = sum_i exp(relu(s_i+c)-m)
// [1026..1028) cm = {c, m}
// [1536..2048) acc (unnormalized output accumulator)
// [2048..3072) pmax (per-block partial max of s)
// [4096..+KK)  s    (s_i = x_i . v)
// memset zeroes the first 2048 floats (v,u,sumU,Z,acc).

__device__ inline float waveSum(float v){
  #pragma unroll
  for(int off = 32; off > 0; off >>= 1) v += __shfl_down(v, off, 64);
  return v;   // total in lane 0
}
__device__ inline float waveMax(float v){
  #pragma unroll
  for(int off = 32; off > 0; off >>= 1) v = fmaxf(v, __shfl_down(v, off, 64));
  return v;
}
__device__ inline float dot8(float4 x0, float4 x1, float4 v0, float4 v1){
  return x0.x*v0.x + x0.y*v0.y + x0.z*v0.z + x0.w*v0.w
       + x1.x*v1.x + x1.y*v1.y + x1.z*v1.z + x1.w*v1.w;
}

// v_j = sum_k W[k,j] a1[k] ; u_j = sum_k W[k,j] a2[k]
// 64 blocks x 512 threads, 8 k-rows per block; 64-way atomic contention only.
__global__ __launch_bounds__(512) void k_vu(const float* __restrict__ W,
                                            const float* __restrict__ a,
                                            float* __restrict__ v,
                                            float* __restrict__ u){
  int j  = threadIdx.x;
  int k0 = blockIdx.x * 8;
  float pv = 0.f, pu = 0.f;
  #pragma unroll
  for(int kk = 0; kk < 8; kk++){
    float w = W[(size_t)(k0 + kk) * MM + j];
    pv += w * a[k0 + kk];
    pu += w * a[MM + k0 + kk];
  }
  atomicAdd(&v[j], pv);
  atomicAdd(&u[j], pu);
}

// Pass 1: s_i = x_i.v (8-row batched butterfly reduce), sumU += x_i.u
// (per-lane register accumulate, no per-row reduce), per-block max of s.
__global__ __launch_bounds__(256) void k_pass1(const float* __restrict__ x,
                                               const float* __restrict__ vv,
                                               const float* __restrict__ uu,
                                               float* __restrict__ s,
                                               float* __restrict__ sumU,
                                               float* __restrict__ pmax){
  __shared__ float lsum[4];
  __shared__ float lmax[4];
  int tid  = threadIdx.x;
  int lane = tid & 63;
  int wid  = tid >> 6;
  int gw   = blockIdx.x * 4 + wid;

  const float4* v4 = (const float4*)vv;
  const float4* u4 = (const float4*)uu;
  float4 v0 = v4[lane],      v1 = v4[64 + lane];
  float4 u0 = u4[lane],      u1 = u4[64 + lane];
  float accU = 0.f;
  float wmax = -3.4e38f;

  int myN = (KK - 1 - gw) / NW + 1;   // rows this wave owns (24 or 25)
  int k = 0;
  for(; k + 8 <= myN; k += 8){
    float d[8];
    #pragma unroll
    for(int r = 0; r < 8; r++){
      size_t row = (size_t)gw + (size_t)(k + r) * NW;
      const float4* xr = (const float4*)(x + row * MM);
      float4 x0 = xr[lane];
      float4 x1 = xr[64 + lane];
      d[r]  = dot8(x0, x1, v0, v1);
      accU += dot8(x0, x1, u0, u1);
    }
    // 8 independent butterfly chains -> latency hidden
    #pragma unroll
    for(int off = 1; off < 64; off <<= 1){
      #pragma unroll
      for(int r = 0; r < 8; r++) d[r] += __shfl_xor(d[r], off, 64);
    }
    float m01 = fmaxf(fmaxf(d[0], d[1]), fmaxf(d[2], d[3]));
    float m23 = fmaxf(fmaxf(d[4], d[5]), fmaxf(d[6], d[7]));
    wmax = fmaxf(wmax, fmaxf(m01, m23));
    // lane l (l<8) selects d[l] and stores s[row_l]
    float s0 = (lane & 1) ? d[1] : d[0];
    float s1 = (lane & 1) ? d[3] : d[2];
    float s2 = (lane & 1) ? d[5] : d[4];
    float s3 = (lane & 1) ? d[7] : d[6];
    float t0 = (lane & 2) ? s1 : s0;
    float t1 = (lane & 2) ? s3 : s2;
    float rr = (lane & 4) ? t1 : t0;
    if(lane < 8) s[(size_t)gw + (size_t)(k + lane) * NW] = rr;
  }
  for(; k < myN; k++){   // remainder (at most 1 row)
    size_t row = (size_t)gw + (size_t)k * NW;
    const float4* xr = (const float4*)(x + row * MM);
    float4 x0 = xr[lane];
    float4 x1 = xr[64 + lane];
    float d = dot8(x0, x1, v0, v1);
    accU += dot8(x0, x1, u0, u1);
    #pragma unroll
    for(int off = 1; off < 64; off <<= 1) d += __shfl_xor(d, off, 64);
    wmax = fmaxf(wmax, d);
    if(lane == 0) s[row] = d;
  }

  float ws_ = waveSum(accU);
  if(lane == 0){ lsum[wid] = ws_; lmax[wid] = wmax; }
  __syncthreads();
  if(tid == 0){
    atomicAdd(sumU, lsum[0] + lsum[1] + lsum[2] + lsum[3]);
    pmax[blockIdx.x] = fmaxf(fmaxf(lmax[0], lmax[1]), fmaxf(lmax[2], lmax[3]));
  }
}

// Single block: c = b.(a1+a2) + sumU/K ; m = max(0, max_i s_i + c)
__global__ __launch_bounds__(512) void k_mid(const float* __restrict__ b,
                                             const float* __restrict__ a,
                                             const float* __restrict__ sumU,
                                             const float* __restrict__ pmax,
                                             float* __restrict__ cm){
  __shared__ float ls[8];
  __shared__ float lm[8];
  int tid = threadIdx.x;
  float t = b[tid] * (a[tid] + a[MM + tid]);
  float wsum = waveSum(t);
  float mx = -3.4e38f;
  for(int i = tid; i < NB1; i += 512) mx = fmaxf(mx, pmax[i]);
  mx = waveMax(mx);
  if((tid & 63) == 0){ ls[tid >> 6] = wsum; lm[tid >> 6] = mx; }
  __syncthreads();
  if(tid == 0){
    float c = sumU[0] * (1.0f / (float)KK), m = -3.4e38f;
    #pragma unroll
    for(int i = 0; i < 8; i++){ c += ls[i]; m = fmaxf(m, lm[i]); }
    cm[0] = c;
    cm[1] = fmaxf(0.f, m + c);   // max of relu(s+c)
  }
}

// Pass 2: acc_j = sum_i w_i x_ij with w_i = exp(relu(s_i+c)-m); Z = sum_i w_i.
__global__ __launch_bounds__(256) void k_pass2(const float* __restrict__ x,
                                               const float* __restrict__ s,
                                               const float* __restrict__ cm,
                                               float* __restrict__ acc,
                                               float* __restrict__ Z){
  __shared__ float lout[512];
  __shared__ float lz[4];
  int tid  = threadIdx.x;
  int lane = tid & 63;
  int wid  = tid >> 6;
  int gw   = blockIdx.x * 4 + wid;
  float c = cm[0], m = cm[1];
  float4 a0 = make_float4(0,0,0,0), a1 = make_float4(0,0,0,0);
  float accZ = 0.f;

  for(int row = gw; row < KK; row += NW){
    float w = __expf(fmaxf(s[row] + c, 0.f) - m);
    const float4* xr = (const float4*)(x + (size_t)row * MM);
    float4 x0 = xr[lane];
    float4 x1 = xr[64 + lane];
    a0.x += w * x0.x; a0.y += w * x0.y; a0.z += w * x0.z; a0.w += w * x0.w;
    a1.x += w * x1.x; a1.y += w * x1.y; a1.z += w * x1.z; a1.w += w * x1.w;
    accZ += w;   // identical across lanes; divided by 64 below
  }

  lout[tid] = 0.f; lout[tid + 256] = 0.f;
  __syncthreads();
  atomicAdd(&lout[lane*4 + 0], a0.x);
  atomicAdd(&lout[lane*4 + 1], a0.y);
  atomicAdd(&lout[lane*4 + 2], a0.z);
  atomicAdd(&lout[lane*4 + 3], a0.w);
  atomicAdd(&lout[256 + lane*4 + 0], a1.x);
  atomicAdd(&lout[256 + lane*4 + 1], a1.y);
  atomicAdd(&lout[256 + lane*4 + 2], a1.z);
  atomicAdd(&lout[256 + lane*4 + 3], a1.w);
  float wz = waveSum(accZ);
  if(lane == 0) lz[wid] = wz;
  __syncthreads();
  atomicAdd(&acc[tid],       lout[tid]);
  atomicAdd(&acc[tid + 256], lout[tid + 256]);
  if(tid == 0) atomicAdd(Z, (lz[0] + lz[1] + lz[2] + lz[3]) * (1.0f / 64.0f));
}

// out_j = acc_j / Z
__global__ __launch_bounds__(512) void k_fin(const float* __restrict__ acc,
                                             const float* __restrict__ Z,
                                             float* __restrict__ out){
  out[threadIdx.x] = acc[threadIdx.x] / Z[0];
}

extern "C" void kernel_launch(void* const* d_in, const int* in_sizes, int n_in,
                              void* d_out, int out_size, void* d_ws, size_t ws_size,
                              hipStream_t stream) {
  const float* x = (const float*)d_in[0];
  const float* W = (const float*)d_in[1];
  const float* b = (const float*)d_in[2];
  const float* a = (const float*)d_in[3];
  float* ws  = (float*)d_ws;
  float* out = (float*)d_out;

  float* v    = ws;
  float* u    = ws + 512;
  float* sumU = ws + 1024;
  float* Z    = ws + 1025;
  float* cm   = ws + 1026;
  float* acc  = ws + 1536;
  float* pmax = ws + 2048;
  float* s    = ws + 4096;

  hipMemsetAsync(ws, 0, 2048 * sizeof(float), stream);  // v,u,sumU,Z,acc

  k_vu   <<<64,   512, 0, stream>>>(W, a, v, u);
  k_pass1<<<NB1,  256, 0, stream>>>(x, v, u, s, sumU, pmax);
  k_mid  <<<1,    512, 0, stream>>>(b, a, sumU, pmax, cm);
  k_pass2<<<NB1,  256, 0, stream>>>(x, s, cm, acc, Z);
  k_fin  <<<1,    512, 0, stream>>>(acc, Z, out);
}

// Round 3
// 345.728 us; speedup vs baseline: 1.0519x; 1.0172x over previous
//
#include <hip/hip_runtime.h>
#include <math.h>

#define MM 512
#define KK 100000
#define NB1 1024               // pass1/pass2 blocks (4 waves each -> 4096 waves)
#define NW  (NB1 * 4)          // total waves in pass kernels

// ws float layout:
// [0..512)     v = W^T a1
// [512..1024)  u = W^T a2
// [1024]       sumU = sum_i x_i . u
// [1025]       Z    = sum_i exp(relu(s_i+c)-m)
// [1026..1028) cm = {c, m}
// [1536..2048) acc (unnormalized output accumulator)
// [2048..3072) pmax (per-block partial max of s; written unconditionally, no zeroing)
// [4096..+KK)  s    (s_i = x_i . v)
// memset zeroes the first 2048 floats (v,u,sumU,Z,cm,acc).

__device__ inline float waveSum(float v){
  #pragma unroll
  for(int off = 32; off > 0; off >>= 1) v += __shfl_down(v, off, 64);
  return v;   // total in lane 0
}
__device__ inline float waveMax(float v){
  #pragma unroll
  for(int off = 32; off > 0; off >>= 1) v = fmaxf(v, __shfl_down(v, off, 64));
  return v;
}
__device__ inline float dot8(float4 x0, float4 x1, float4 v0, float4 v1){
  return x0.x*v0.x + x0.y*v0.y + x0.z*v0.z + x0.w*v0.w
       + x1.x*v1.x + x1.y*v1.y + x1.z*v1.z + x1.w*v1.w;
}

// v_j = sum_k W[k,j] a1[k] ; u_j = sum_k W[k,j] a2[k]
__global__ __launch_bounds__(512) void k_vu(const float* __restrict__ W,
                                            const float* __restrict__ a,
                                            float* __restrict__ v,
                                            float* __restrict__ u){
  int j  = threadIdx.x;
  int k0 = blockIdx.x * 8;
  float pv = 0.f, pu = 0.f;
  #pragma unroll
  for(int kk = 0; kk < 8; kk++){
    float w = W[(size_t)(k0 + kk) * MM + j];
    pv += w * a[k0 + kk];
    pu += w * a[MM + k0 + kk];
  }
  atomicAdd(&v[j], pv);
  atomicAdd(&u[j], pu);
}

// Pass 1: s_i = x_i.v (8-row batched butterfly reduce), sumU += x_i.u
// (per-lane register accumulate), per-block max of s.
__global__ __launch_bounds__(256) void k_pass1(const float* __restrict__ x,
                                               const float* __restrict__ vv,
                                               const float* __restrict__ uu,
                                               float* __restrict__ s,
                                               float* __restrict__ sumU,
                                               float* __restrict__ pmax){
  __shared__ float lsum[4];
  __shared__ float lmax[4];
  int tid  = threadIdx.x;
  int lane = tid & 63;
  int wid  = tid >> 6;
  int gw   = blockIdx.x * 4 + wid;

  const float4* v4 = (const float4*)vv;
  const float4* u4 = (const float4*)uu;
  float4 v0 = v4[lane],      v1 = v4[64 + lane];
  float4 u0 = u4[lane],      u1 = u4[64 + lane];
  float accU = 0.f;
  float wmax = -3.4e38f;

  int myN = (KK - 1 - gw) / NW + 1;   // rows this wave owns (24 or 25)
  int k = 0;
  for(; k + 8 <= myN; k += 8){
    float d[8];
    #pragma unroll
    for(int r = 0; r < 8; r++){
      size_t row = (size_t)gw + (size_t)(k + r) * NW;
      const float4* xr = (const float4*)(x + row * MM);
      float4 x0 = xr[lane];
      float4 x1 = xr[64 + lane];
      d[r]  = dot8(x0, x1, v0, v1);
      accU += dot8(x0, x1, u0, u1);
    }
    #pragma unroll
    for(int off = 1; off < 64; off <<= 1){
      #pragma unroll
      for(int r = 0; r < 8; r++) d[r] += __shfl_xor(d[r], off, 64);
    }
    float m01 = fmaxf(fmaxf(d[0], d[1]), fmaxf(d[2], d[3]));
    float m23 = fmaxf(fmaxf(d[4], d[5]), fmaxf(d[6], d[7]));
    wmax = fmaxf(wmax, fmaxf(m01, m23));
    // lane l (l<8) selects d[l] and stores s[row_l]
    float s0 = (lane & 1) ? d[1] : d[0];
    float s1 = (lane & 1) ? d[3] : d[2];
    float s2 = (lane & 1) ? d[5] : d[4];
    float s3 = (lane & 1) ? d[7] : d[6];
    float t0 = (lane & 2) ? s1 : s0;
    float t1 = (lane & 2) ? s3 : s2;
    float rr = (lane & 4) ? t1 : t0;
    if(lane < 8) s[(size_t)gw + (size_t)(k + lane) * NW] = rr;
  }
  for(; k < myN; k++){   // remainder (at most 1 row)
    size_t row = (size_t)gw + (size_t)k * NW;
    const float4* xr = (const float4*)(x + row * MM);
    float4 x0 = xr[lane];
    float4 x1 = xr[64 + lane];
    float d = dot8(x0, x1, v0, v1);
    accU += dot8(x0, x1, u0, u1);
    #pragma unroll
    for(int off = 1; off < 64; off <<= 1) d += __shfl_xor(d, off, 64);
    wmax = fmaxf(wmax, d);
    if(lane == 0) s[row] = d;
  }

  float ws_ = waveSum(accU);
  if(lane == 0){ lsum[wid] = ws_; lmax[wid] = wmax; }
  __syncthreads();
  if(tid == 0){
    atomicAdd(sumU, lsum[0] + lsum[1] + lsum[2] + lsum[3]);
    pmax[blockIdx.x] = fmaxf(fmaxf(lmax[0], lmax[1]), fmaxf(lmax[2], lmax[3]));
  }
}

// Single block: c = b.(a1+a2) + sumU/K ; m = max(0, max_i s_i + c)
__global__ __launch_bounds__(512) void k_mid(const float* __restrict__ b,
                                             const float* __restrict__ a,
                                             const float* __restrict__ sumU,
                                             const float* __restrict__ pmax,
                                             float* __restrict__ cm){
  __shared__ float ls[8];
  __shared__ float lm[8];
  int tid = threadIdx.x;
  float t = b[tid] * (a[tid] + a[MM + tid]);
  float wsum = waveSum(t);
  float mx = -3.4e38f;
  for(int i = tid; i < NB1; i += 512) mx = fmaxf(mx, pmax[i]);
  mx = waveMax(mx);
  if((tid & 63) == 0){ ls[tid >> 6] = wsum; lm[tid >> 6] = mx; }
  __syncthreads();
  if(tid == 0){
    float c = sumU[0] * (1.0f / (float)KK), m = -3.4e38f;
    #pragma unroll
    for(int i = 0; i < 8; i++){ c += ls[i]; m = fmaxf(m, lm[i]); }
    cm[0] = c;
    cm[1] = fmaxf(0.f, m + c);   // max of relu(s+c)
  }
}

// Pass 2 (8-row batched): acc_j = sum_i w_i x_ij, w_i = exp(relu(s_i+c)-m);
// Z = sum_i w_i.  x should be L3-resident after pass1 (204.8 MB < 256 MiB).
__global__ __launch_bounds__(256) void k_pass2(const float* __restrict__ x,
                                               const float* __restrict__ s,
                                               const float* __restrict__ cm,
                                               float* __restrict__ acc,
                                               float* __restrict__ Z){
  __shared__ float lout[512];
  __shared__ float lz[4];
  int tid  = threadIdx.x;
  int lane = tid & 63;
  int wid  = tid >> 6;
  int gw   = blockIdx.x * 4 + wid;
  float c = cm[0], m = cm[1];
  float4 a0 = make_float4(0,0,0,0), a1 = make_float4(0,0,0,0);
  float accZ = 0.f;

  int myN = (KK - 1 - gw) / NW + 1;
  int k = 0;
  for(; k + 8 <= myN; k += 8){
    float w[8];
    #pragma unroll
    for(int r = 0; r < 8; r++)
      w[r] = s[(size_t)gw + (size_t)(k + r) * NW];
    #pragma unroll
    for(int r = 0; r < 8; r++){
      w[r] = __expf(fmaxf(w[r] + c, 0.f) - m);
      accZ += w[r];
    }
    #pragma unroll
    for(int r = 0; r < 8; r++){
      size_t row = (size_t)gw + (size_t)(k + r) * NW;
      const float4* xr = (const float4*)(x + row * MM);
      float4 x0 = xr[lane];
      float4 x1 = xr[64 + lane];
      a0.x += w[r] * x0.x; a0.y += w[r] * x0.y; a0.z += w[r] * x0.z; a0.w += w[r] * x0.w;
      a1.x += w[r] * x1.x; a1.y += w[r] * x1.y; a1.z += w[r] * x1.z; a1.w += w[r] * x1.w;
    }
  }
  for(; k < myN; k++){
    size_t row = (size_t)gw + (size_t)k * NW;
    float w = __expf(fmaxf(s[row] + c, 0.f) - m);
    accZ += w;
    const float4* xr = (const float4*)(x + row * MM);
    float4 x0 = xr[lane];
    float4 x1 = xr[64 + lane];
    a0.x += w * x0.x; a0.y += w * x0.y; a0.z += w * x0.z; a0.w += w * x0.w;
    a1.x += w * x1.x; a1.y += w * x1.y; a1.z += w * x1.z; a1.w += w * x1.w;
  }

  lout[tid] = 0.f; lout[tid + 256] = 0.f;
  __syncthreads();
  atomicAdd(&lout[lane*4 + 0], a0.x);
  atomicAdd(&lout[lane*4 + 1], a0.y);
  atomicAdd(&lout[lane*4 + 2], a0.z);
  atomicAdd(&lout[lane*4 + 3], a0.w);
  atomicAdd(&lout[256 + lane*4 + 0], a1.x);
  atomicAdd(&lout[256 + lane*4 + 1], a1.y);
  atomicAdd(&lout[256 + lane*4 + 2], a1.z);
  atomicAdd(&lout[256 + lane*4 + 3], a1.w);
  float wz = waveSum(accZ);
  if(lane == 0) lz[wid] = wz;
  __syncthreads();
  atomicAdd(&acc[tid],       lout[tid]);
  atomicAdd(&acc[tid + 256], lout[tid + 256]);
  if(tid == 0) atomicAdd(Z, (lz[0] + lz[1] + lz[2] + lz[3]) * (1.0f / 64.0f));
}

// out_j = acc_j / Z
__global__ __launch_bounds__(512) void k_fin(const float* __restrict__ acc,
                                             const float* __restrict__ Z,
                                             float* __restrict__ out){
  out[threadIdx.x] = acc[threadIdx.x] / Z[0];
}

extern "C" void kernel_launch(void* const* d_in, const int* in_sizes, int n_in,
                              void* d_out, int out_size, void* d_ws, size_t ws_size,
                              hipStream_t stream) {
  const float* x = (const float*)d_in[0];
  const float* W = (const float*)d_in[1];
  const float* b = (const float*)d_in[2];
  const float* a = (const float*)d_in[3];
  float* ws  = (float*)d_ws;
  float* out = (float*)d_out;

  float* v    = ws;
  float* u    = ws + 512;
  float* sumU = ws + 1024;
  float* Z    = ws + 1025;
  float* cm   = ws + 1026;
  float* acc  = ws + 1536;
  float* pmax = ws + 2048;
  float* s    = ws + 4096;

  hipMemsetAsync(ws, 0, 2048 * sizeof(float), stream);  // v,u,sumU,Z,cm,acc

  k_vu   <<<64,   512, 0, stream>>>(W, a, v, u);
  k_pass1<<<NB1,  256, 0, stream>>>(x, v, u, s, sumU, pmax);
  k_mid  <<<1,    512, 0, stream>>>(b, a, sumU, pmax, cm);
  k_pass2<<<NB1,  256, 0, stream>>>(x, s, cm, acc, Z);
  k_fin  <<<1,    512, 0, stream>>>(acc, Z, out);
}

// Round 4
// 335.282 us; speedup vs baseline: 1.0846x; 1.0312x over previous
//
#include <hip/hip_runtime.h>
#include <math.h>

#define MM 512
#define KK 100000
#define NB1 1024               // pass1/pass2 blocks (4 waves each -> 4096 waves)
#define NW  (NB1 * 4)          // total waves in pass kernels
#define NOUT 16                // k_out blocks

// ws float layout:
// [0..512)     v = W^T a1
// [512..1024)  u = W^T a2
// [1024]       sumU = sum_i x_i . u
// [1025]       Z    = sum_i exp(relu(s_i+c)-m) (atomic-accumulated, /64)
// [1026]       done-counter for k_out (int)
// [1536..2048) acc (k_out cross-block accumulator)
// [2048..3072) pmax (per-block partial max of s; written unconditionally)
// [4096..+KK)  s    (s_i = x_i . v)
// [131072..655360) part: per-block unnormalized colsums, part[b][512]
// memset zeroes the first 2048 floats (v,u,sumU,Z,counter,acc).

__device__ inline float waveSum(float v){
  #pragma unroll
  for(int off = 32; off > 0; off >>= 1) v += __shfl_down(v, off, 64);
  return v;   // total in lane 0
}
__device__ inline float waveMax(float v){
  #pragma unroll
  for(int off = 32; off > 0; off >>= 1) v = fmaxf(v, __shfl_down(v, off, 64));
  return v;
}
__device__ inline float dot8(float4 x0, float4 x1, float4 v0, float4 v1){
  return x0.x*v0.x + x0.y*v0.y + x0.z*v0.z + x0.w*v0.w
       + x1.x*v1.x + x1.y*v1.y + x1.z*v1.z + x1.w*v1.w;
}

// v_j = sum_k W[k,j] a1[k] ; u_j = sum_k W[k,j] a2[k]
__global__ __launch_bounds__(512) void k_vu(const float* __restrict__ W,
                                            const float* __restrict__ a,
                                            float* __restrict__ v,
                                            float* __restrict__ u){
  int j  = threadIdx.x;
  int k0 = blockIdx.x * 8;
  float pv = 0.f, pu = 0.f;
  #pragma unroll
  for(int kk = 0; kk < 8; kk++){
    float w = W[(size_t)(k0 + kk) * MM + j];
    pv += w * a[k0 + kk];
    pu += w * a[MM + k0 + kk];
  }
  atomicAdd(&v[j], pv);
  atomicAdd(&u[j], pu);
}

// Pass 1: s_i = x_i.v (8-row batched butterfly reduce), sumU += x_i.u,
// per-block max of s.
__global__ __launch_bounds__(256) void k_pass1(const float* __restrict__ x,
                                               const float* __restrict__ vv,
                                               const float* __restrict__ uu,
                                               float* __restrict__ s,
                                               float* __restrict__ sumU,
                                               float* __restrict__ pmax){
  __shared__ float lsum[4];
  __shared__ float lmax[4];
  int tid  = threadIdx.x;
  int lane = tid & 63;
  int wid  = tid >> 6;
  int gw   = blockIdx.x * 4 + wid;

  const float4* v4 = (const float4*)vv;
  const float4* u4 = (const float4*)uu;
  float4 v0 = v4[lane],      v1 = v4[64 + lane];
  float4 u0 = u4[lane],      u1 = u4[64 + lane];
  float accU = 0.f;
  float wmax = -3.4e38f;

  int myN = (KK - 1 - gw) / NW + 1;   // rows this wave owns (24 or 25)
  int k = 0;
  for(; k + 8 <= myN; k += 8){
    float d[8];
    #pragma unroll
    for(int r = 0; r < 8; r++){
      size_t row = (size_t)gw + (size_t)(k + r) * NW;
      const float4* xr = (const float4*)(x + row * MM);
      float4 x0 = xr[lane];
      float4 x1 = xr[64 + lane];
      d[r]  = dot8(x0, x1, v0, v1);
      accU += dot8(x0, x1, u0, u1);
    }
    #pragma unroll
    for(int off = 1; off < 64; off <<= 1){
      #pragma unroll
      for(int r = 0; r < 8; r++) d[r] += __shfl_xor(d[r], off, 64);
    }
    float m01 = fmaxf(fmaxf(d[0], d[1]), fmaxf(d[2], d[3]));
    float m23 = fmaxf(fmaxf(d[4], d[5]), fmaxf(d[6], d[7]));
    wmax = fmaxf(wmax, fmaxf(m01, m23));
    float s0 = (lane & 1) ? d[1] : d[0];
    float s1 = (lane & 1) ? d[3] : d[2];
    float s2 = (lane & 1) ? d[5] : d[4];
    float s3 = (lane & 1) ? d[7] : d[6];
    float t0 = (lane & 2) ? s1 : s0;
    float t1 = (lane & 2) ? s3 : s2;
    float rr = (lane & 4) ? t1 : t0;
    if(lane < 8) s[(size_t)gw + (size_t)(k + lane) * NW] = rr;
  }
  for(; k < myN; k++){
    size_t row = (size_t)gw + (size_t)k * NW;
    const float4* xr = (const float4*)(x + row * MM);
    float4 x0 = xr[lane];
    float4 x1 = xr[64 + lane];
    float d = dot8(x0, x1, v0, v1);
    accU += dot8(x0, x1, u0, u1);
    #pragma unroll
    for(int off = 1; off < 64; off <<= 1) d += __shfl_xor(d, off, 64);
    wmax = fmaxf(wmax, d);
    if(lane == 0) s[row] = d;
  }

  float ws_ = waveSum(accU);
  if(lane == 0){ lsum[wid] = ws_; lmax[wid] = wmax; }
  __syncthreads();
  if(tid == 0){
    atomicAdd(sumU, lsum[0] + lsum[1] + lsum[2] + lsum[3]);
    pmax[blockIdx.x] = fmaxf(fmaxf(lmax[0], lmax[1]), fmaxf(lmax[2], lmax[3]));
  }
}

// Pass 2 (+mid folded): each block computes c,m itself, streams its rows,
// writes per-block colsum partials to part[b][512] (NO global atomics),
// one atomicAdd into Z per block.
__global__ __launch_bounds__(256) void k_pass2(const float* __restrict__ x,
                                               const float* __restrict__ s,
                                               const float* __restrict__ b,
                                               const float* __restrict__ a,
                                               const float* __restrict__ sumU,
                                               const float* __restrict__ pmax,
                                               float* __restrict__ part,
                                               float* __restrict__ Z){
  __shared__ float red[8];
  __shared__ float lw[2048];   // 4 waves x 64 lanes x 8 cols
  int tid  = threadIdx.x;
  int lane = tid & 63;
  int wid  = tid >> 6;
  int gw   = blockIdx.x * 4 + wid;

  // ---- prologue: c = b.(a1+a2) + sumU/K ; m = max(0, max_i s_i + c) ----
  float tp = b[tid]       * (a[tid]       + a[MM + tid])
           + b[tid + 256] * (a[tid + 256] + a[MM + tid + 256]);
  float mx = fmaxf(fmaxf(pmax[tid], pmax[tid + 256]),
                   fmaxf(pmax[tid + 512], pmax[tid + 768]));
  float wsum = waveSum(tp);
  mx = waveMax(mx);
  if(lane == 0){ red[wid] = wsum; red[4 + wid] = mx; }
  __syncthreads();
  float c = sumU[0] * (1.0f / (float)KK) + red[0] + red[1] + red[2] + red[3];
  float m = fmaxf(fmaxf(red[4], red[5]), fmaxf(red[6], red[7]));
  m = fmaxf(0.f, m + c);

  // ---- main streaming loop (8-row batched) ----
  float4 a0 = make_float4(0,0,0,0), a1 = make_float4(0,0,0,0);
  float accZ = 0.f;
  int myN = (KK - 1 - gw) / NW + 1;
  int k = 0;
  for(; k + 8 <= myN; k += 8){
    float w[8];
    #pragma unroll
    for(int r = 0; r < 8; r++)
      w[r] = s[(size_t)gw + (size_t)(k + r) * NW];
    #pragma unroll
    for(int r = 0; r < 8; r++){
      w[r] = __expf(fmaxf(w[r] + c, 0.f) - m);
      accZ += w[r];
    }
    #pragma unroll
    for(int r = 0; r < 8; r++){
      size_t row = (size_t)gw + (size_t)(k + r) * NW;
      const float4* xr = (const float4*)(x + row * MM);
      float4 x0 = xr[lane];
      float4 x1 = xr[64 + lane];
      a0.x += w[r] * x0.x; a0.y += w[r] * x0.y; a0.z += w[r] * x0.z; a0.w += w[r] * x0.w;
      a1.x += w[r] * x1.x; a1.y += w[r] * x1.y; a1.z += w[r] * x1.z; a1.w += w[r] * x1.w;
    }
  }
  for(; k < myN; k++){
    size_t row = (size_t)gw + (size_t)k * NW;
    float w = __expf(fmaxf(s[row] + c, 0.f) - m);
    accZ += w;
    const float4* xr = (const float4*)(x + row * MM);
    float4 x0 = xr[lane];
    float4 x1 = xr[64 + lane];
    a0.x += w * x0.x; a0.y += w * x0.y; a0.z += w * x0.z; a0.w += w * x0.w;
    a1.x += w * x1.x; a1.y += w * x1.y; a1.z += w * x1.z; a1.w += w * x1.w;
  }

  // ---- tail: cross-wave sum via plain LDS, coalesced non-atomic output ----
  float zw = waveSum(accZ);
  __syncthreads();                 // red's first use fully read above
  float4* lw4 = (float4*)lw;
  lw4[wid * 128 + lane * 2]     = a0;   // lane l holds cols 4l+q   (q=0..3)
  lw4[wid * 128 + lane * 2 + 1] = a1;   // and cols 256+4l+q
  if(lane == 0) red[wid] = zw;
  __syncthreads();
  int l = tid >> 2, q = tid & 3;
  float s0 = lw[0*512 + l*8 + q] + lw[1*512 + l*8 + q]
           + lw[2*512 + l*8 + q] + lw[3*512 + l*8 + q];
  float s1 = lw[0*512 + l*8 + 4 + q] + lw[1*512 + l*8 + 4 + q]
           + lw[2*512 + l*8 + 4 + q] + lw[3*512 + l*8 + 4 + q];
  part[(size_t)blockIdx.x * 512 + tid]       = s0;
  part[(size_t)blockIdx.x * 512 + 256 + tid] = s1;
  if(tid == 0)
    atomicAdd(Z, (red[0] + red[1] + red[2] + red[3]) * (1.0f / 64.0f));
}

// Reduce part[1024][512] -> acc, last block divides by Z and writes out.
__global__ __launch_bounds__(256) void k_out(const float* __restrict__ part,
                                             float* __restrict__ acc,
                                             const float* __restrict__ Z,
                                             int* __restrict__ cnt,
                                             float* __restrict__ out){
  __shared__ int lastf;
  int tid = threadIdx.x;
  const float* p = part + (size_t)blockIdx.x * (NB1 / NOUT) * 512;
  float s0 = 0.f, s1 = 0.f;
  #pragma unroll 8
  for(int bb = 0; bb < NB1 / NOUT; bb++){
    s0 += p[bb * 512 + tid];
    s1 += p[bb * 512 + 256 + tid];
  }
  atomicAdd(&acc[tid],       s0);
  atomicAdd(&acc[tid + 256], s1);
  __threadfence();
  if(tid == 0) lastf = (atomicAdd(cnt, 1) == NOUT - 1) ? 1 : 0;
  __syncthreads();
  if(lastf){
    float z = Z[0];   // written by previous dispatch — safe plain read
    float v0 = atomicAdd(&acc[tid],       0.0f);  // coherent read of atomics
    float v1 = atomicAdd(&acc[tid + 256], 0.0f);
    out[tid]       = v0 / z;
    out[tid + 256] = v1 / z;
  }
}

extern "C" void kernel_launch(void* const* d_in, const int* in_sizes, int n_in,
                              void* d_out, int out_size, void* d_ws, size_t ws_size,
                              hipStream_t stream) {
  const float* x = (const float*)d_in[0];
  const float* W = (const float*)d_in[1];
  const float* b = (const float*)d_in[2];
  const float* a = (const float*)d_in[3];
  float* ws  = (float*)d_ws;
  float* out = (float*)d_out;

  float* v    = ws;
  float* u    = ws + 512;
  float* sumU = ws + 1024;
  float* Z    = ws + 1025;
  int*   cnt  = (int*)(ws + 1026);
  float* acc  = ws + 1536;
  float* pmax = ws + 2048;
  float* s    = ws + 4096;
  float* part = ws + 131072;

  hipMemsetAsync(ws, 0, 2048 * sizeof(float), stream);  // v,u,sumU,Z,cnt,acc

  k_vu   <<<64,   512, 0, stream>>>(W, a, v, u);
  k_pass1<<<NB1,  256, 0, stream>>>(x, v, u, s, sumU, pmax);
  k_pass2<<<NB1,  256, 0, stream>>>(x, s, b, a, sumU, pmax, part, Z);
  k_out  <<<NOUT, 256, 0, stream>>>(part, acc, Z, cnt, out);
}